// Round 7
// baseline (76.883 us; speedup 1.0000x reference)
//
#include <hip/hip_runtime.h>
#include <stdint.h>
#include <stddef.h>

typedef __attribute__((ext_vector_type(4))) float    f32x4;
typedef __attribute__((ext_vector_type(4))) uint32_t u32x4;
typedef __attribute__((ext_vector_type(8))) __bf16   bf16x8;

#define CGS   2944      // bytes per cgroup plane (10 rows x 9 cols x 2 par x 16B = 2880 + 64 pad)
                        // 2944 % 512 == 384 -> compute ds_read_b128 lanes tile banks uniformly 2-way (free)
#define NFRAG 15360     // 15 (dir,tap) * 2 kk * 4 mtile * 64 lanes

// tap (kr,kc) per f = dir*5+tap  (dir: 0=up,1=left,2=right)
__device__ __constant__ uint8_t TAPR[15] = {0,0,1,2,2, 1,2,2,2,3, 1,2,2,2,3};
__device__ __constant__ uint8_t TAPC[15] = {0,1,1,1,2, 1,0,1,2,1, 1,1,2,3,3};

// periodic copies split by row-half (h=0: padded rows 0..9, h=1: 8..17; lrow = padded - 8h).
// L = src inside this half's LDS; G = src read from global x (src sites are interior x values).
__device__ __constant__ uint8_t NLC[2]      = {5, 7};
__device__ __constant__ uint8_t LDL[2][7]   = {{6,7,8,8,6,0,0},        {0,2,3,4,4,2,0}};
__device__ __constant__ uint8_t LDCc[2][7]  = {{13,13,14,1,0,0,0},     {14,15,15,16,3,2,1}};
__device__ __constant__ uint8_t LSL[2][7]   = {{6,7,8,8,6,0,0},        {0,2,3,4,4,2,0}};
__device__ __constant__ uint8_t LSC[2][7]   = {{1,1,2,13,12,0,0},      {2,3,3,4,15,14,13}};
__device__ __constant__ uint8_t GDL[2][10]  = {{1,1,2,3,4,4,4,4,3,2},  {6,6,7,8,9,9,8,7,6,6}};
__device__ __constant__ uint8_t GDCc[2][10] = {{3,5,7,9,10,11,0,1,1,2},{15,16,15,14,13,11,9,7,6,5}};
__device__ __constant__ uint8_t GXR[2][10]  = {{12,12,13,14,15,15,15,15,14,13},{1,1,2,3,4,4,3,2,1,1}};
__device__ __constant__ uint8_t GXC[2][10]  = {{14,4,6,8,9,10,11,12,12,13},    {2,3,2,1,0,10,8,6,5,4}};

__device__ __forceinline__ uint32_t pk2(float a, float b) {
    return (uint32_t)__builtin_bit_cast(uint16_t, (__bf16)a)
         | ((uint32_t)__builtin_bit_cast(uint16_t, (__bf16)b) << 16);
}

// byte offset within a cgroup plane: [parity][lrow][col/2], 16 B slots
__device__ __forceinline__ int slotb(int lr, int c) {
    return (c & 1) * 1440 + lr * 144 + (c >> 1) * 16;
}

// ---------------- weight packing: A-fragment layout for mfma_f32_16x16x32_bf16 ----------------
__global__ __launch_bounds__(256) void pack_w(const float* __restrict__ wu,
                                              const float* __restrict__ wl,
                                              const float* __restrict__ wr,
                                              uint16_t* __restrict__ pw) {
    int fid = blockIdx.x * 256 + threadIdx.x;
    if (fid >= NFRAG) return;
    int lane = fid & 63;
    int mt   = (fid >> 6) & 3;
    int kk   = (fid >> 8) & 1;
    int td   = fid >> 9;                 // 0..14 = dir*5+tap
    const float* w = (td < 5) ? wu : (td < 10) ? wl : wr;
    int o  = mt * 16 + (lane & 15);
    int cb = kk * 32 + (lane >> 4) * 8;
    int kr = TAPR[td], kc = TAPC[td];
    const float* src = w + ((size_t)o * 64 + cb) * 16 + kr * 4 + kc;
    uint32_t d[4];
#pragma unroll
    for (int p = 0; p < 4; ++p)
        d[p] = pk2(src[(2 * p) * 16], src[(2 * p + 1) * 16]);
    u32x4 v = {d[0], d[1], d[2], d[3]};
    *(u32x4*)(pw + (size_t)fid * 8) = v;
}

// Block = (batch, row-half). 23.5 KB LDS -> 6 blocks/CU = 24 waves/CU.
__global__ __launch_bounds__(256, 6) void kagome_main(const float* __restrict__ x,
                                                      const uint16_t* __restrict__ pw,
                                                      const float* __restrict__ bu,
                                                      const float* __restrict__ bl,
                                                      const float* __restrict__ br,
                                                      float* __restrict__ out) {
    __shared__ __align__(16) uint8_t lds[8 * CGS];
    const int tid = threadIdx.x;
    const int b   = blockIdx.x >> 1;
    const int h   = blockIdx.x & 1;      // 0: out rows 0-7, 1: rows 8-15
    const float* xb = x + (size_t)b * 16384;

    // staging task: qc = col quad, cg = channel group, r = local x-row (0..8)
    const int qc = tid & 3;
    const int cg = (tid >> 2) & 7;
    const int r  = tid >> 5;             // 0..7 (r=8 via tid<32 second task)
    const int xr0 = 7 * h;               // x rows xr0 .. xr0+8

    // ---- issue ALL global loads upfront ----
    f32x4 v[8], v2[8];
#pragma unroll
    for (int ch = 0; ch < 8; ++ch)
        v[ch] = *(const f32x4*)(xb + (cg * 8 + ch) * 256 + (xr0 + r) * 16 + qc * 4);
    if (tid < 32) {
        const int qc2 = tid & 3, cg2 = tid >> 2;
#pragma unroll
        for (int ch = 0; ch < 8; ++ch)
            v2[ch] = *(const f32x4*)(xb + (cg2 * 8 + ch) * 256 + (xr0 + 8) * 16 + qc2 * 4);
    }
    const int NL = NLC[h];
    const int cpair = tid >> 3, ccg = tid & 7;      // copy-task mapping
    float g[8];
    if (cpair >= NL && cpair < NL + 10) {
        const int gi = cpair - NL;
        const float* gp = xb + (size_t)ccg * 8 * 256 + GXR[h][gi] * 16 + GXC[h][gi];
#pragma unroll
        for (int ch = 0; ch < 8; ++ch) g[ch] = gp[ch * 256];
    }

    // ---- pack interior rows into LDS ----
    {
        uint8_t* base = lds + cg * CGS;
        const int lr = r + 1 - h;
#pragma unroll
        for (int e = 0; e < 4; ++e) {
            const int c = 4 * qc + e + 1;
            u32x4 w = {pk2(v[0][e], v[1][e]), pk2(v[2][e], v[3][e]),
                       pk2(v[4][e], v[5][e]), pk2(v[6][e], v[7][e])};
            *(u32x4*)(base + slotb(lr, c)) = w;
        }
        if (tid < 32) {
            const int qc2 = tid & 3, cg2 = tid >> 2;
            uint8_t* base2 = lds + cg2 * CGS;
            const int lr2 = 9 - h;
#pragma unroll
            for (int e = 0; e < 4; ++e) {
                const int c = 4 * qc2 + e + 1;
                u32x4 w = {pk2(v2[0][e], v2[1][e]), pk2(v2[2][e], v2[3][e]),
                           pk2(v2[4][e], v2[5][e]), pk2(v2[6][e], v2[7][e])};
                *(u32x4*)(base2 + slotb(lr2, c)) = w;
            }
        }
        // zero the 36 border sites of this half (x8 cgroups = 288 tasks)
        u32x4 z = {0, 0, 0, 0};
#pragma unroll
        for (int i = 0; i < 2; ++i) {
            int idx = tid + 256 * i;
            if (idx < 288) {
                int s = idx >> 3, zcg = idx & 7;
                int lr, c;
                if (s < 18) { lr = h ? 9 : 0; c = s; }
                else        { int k2 = s - 18; lr = (k2 >> 1) + (1 - h); c = (k2 & 1) * 17; }
                *(u32x4*)(lds + zcg * CGS + slotb(lr, c)) = z;
            }
        }
    }
    __syncthreads();

    // ---- periodic copies: LDS-src and global-src ----
    if (cpair < NL) {
        u32x4 w = *(const u32x4*)(lds + ccg * CGS + slotb(LSL[h][cpair], LSC[h][cpair]));
        *(u32x4*)(lds + ccg * CGS + slotb(LDL[h][cpair], LDCc[h][cpair])) = w;
    } else if (cpair < NL + 10) {
        const int gi = cpair - NL;
        u32x4 w = {pk2(g[0], g[1]), pk2(g[2], g[3]), pk2(g[4], g[5]), pk2(g[6], g[7])};
        *(u32x4*)(lds + ccg * CGS + slotb(GDL[h][gi], GDCc[h][gi])) = w;
    }
    __syncthreads();

    // ---- compute: wave wid owns out channels [16wid,16wid+16), rows 8h..8h+7 ----
    const int l   = tid & 63;
    const int wid = tid >> 6;
    const int q   = l >> 4;        // channel quarter
    const int io  = (l >> 3) & 1;  // row-pair within ntl
    const int j   = l & 7;         // conv output column

    f32x4 acc[3][2];
#pragma unroll
    for (int d2 = 0; d2 < 3; ++d2)
#pragma unroll
        for (int n2 = 0; n2 < 2; ++n2) acc[d2][n2] = (f32x4){0.f, 0.f, 0.f, 0.f};

    const uint16_t* pwl = pw + (size_t)l * 8;

#pragma unroll
    for (int kk = 0; kk < 2; ++kk) {
        bf16x8 aw[15];
#pragma unroll
        for (int f2 = 0; f2 < 15; ++f2) {
            u32x4 t = *(const u32x4*)(pwl + (size_t)((f2 * 2 + kk) * 4 + wid) * 512);
            aw[f2] = __builtin_bit_cast(bf16x8, t);
        }
        const uint8_t* lb = lds + (kk * 4 + q) * CGS + io * 288 + j * 16;
#pragma unroll
        for (int ntl = 0; ntl < 2; ++ntl) {
            // B fragment at padded-local pixel (4*ntl + 2*io + dr, 2*j + dc)
#define BRD(dr, dc) __builtin_bit_cast(bf16x8, *(const u32x4*)(lb + ((dc) & 1) * 1440 + (4 * ntl + (dr)) * 144 + ((dc) >> 1) * 16))
            bf16x8 b00 = BRD(0, 0);
            acc[0][ntl] = __builtin_amdgcn_mfma_f32_16x16x32_bf16(aw[0], b00, acc[0][ntl], 0, 0, 0);
            bf16x8 b01 = BRD(0, 1);
            acc[0][ntl] = __builtin_amdgcn_mfma_f32_16x16x32_bf16(aw[1], b01, acc[0][ntl], 0, 0, 0);
            bf16x8 b11 = BRD(1, 1);
            acc[0][ntl] = __builtin_amdgcn_mfma_f32_16x16x32_bf16(aw[2],  b11, acc[0][ntl], 0, 0, 0);
            acc[1][ntl] = __builtin_amdgcn_mfma_f32_16x16x32_bf16(aw[5],  b11, acc[1][ntl], 0, 0, 0);
            acc[2][ntl] = __builtin_amdgcn_mfma_f32_16x16x32_bf16(aw[10], b11, acc[2][ntl], 0, 0, 0);
            bf16x8 b20 = BRD(2, 0);
            acc[1][ntl] = __builtin_amdgcn_mfma_f32_16x16x32_bf16(aw[6],  b20, acc[1][ntl], 0, 0, 0);
            bf16x8 b21 = BRD(2, 1);
            acc[0][ntl] = __builtin_amdgcn_mfma_f32_16x16x32_bf16(aw[3],  b21, acc[0][ntl], 0, 0, 0);
            acc[1][ntl] = __builtin_amdgcn_mfma_f32_16x16x32_bf16(aw[7],  b21, acc[1][ntl], 0, 0, 0);
            acc[2][ntl] = __builtin_amdgcn_mfma_f32_16x16x32_bf16(aw[11], b21, acc[2][ntl], 0, 0, 0);
            bf16x8 b22 = BRD(2, 2);
            acc[0][ntl] = __builtin_amdgcn_mfma_f32_16x16x32_bf16(aw[4],  b22, acc[0][ntl], 0, 0, 0);
            acc[1][ntl] = __builtin_amdgcn_mfma_f32_16x16x32_bf16(aw[8],  b22, acc[1][ntl], 0, 0, 0);
            acc[2][ntl] = __builtin_amdgcn_mfma_f32_16x16x32_bf16(aw[12], b22, acc[2][ntl], 0, 0, 0);
            bf16x8 b23 = BRD(2, 3);
            acc[2][ntl] = __builtin_amdgcn_mfma_f32_16x16x32_bf16(aw[13], b23, acc[2][ntl], 0, 0, 0);
            bf16x8 b31 = BRD(3, 1);
            acc[1][ntl] = __builtin_amdgcn_mfma_f32_16x16x32_bf16(aw[9],  b31, acc[1][ntl], 0, 0, 0);
            bf16x8 b33 = BRD(3, 3);
            acc[2][ntl] = __builtin_amdgcn_mfma_f32_16x16x32_bf16(aw[14], b33, acc[2][ntl], 0, 0, 0);
#undef BRD
        }
    }

    // ---- epilogue: bias, OUT_MASK, lane-paired full-line nontemporal stores ----
    float bias0[4], bias1[4], bias2[4];
#pragma unroll
    for (int rr = 0; rr < 4; ++rr) {
        int o = wid * 16 + q * 4 + rr;
        bias0[rr] = bu[o]; bias1[rr] = bl[o]; bias2[rr] = br[o];
    }

    constexpr uint32_t RM[16] = {0x0008, 0x003C, 0x00FC, 0x01FE, 0x07FF, 0x0FFF, 0x0FFF, 0x1FFE,
                                 0x3FFE, 0xBFFC, 0xBFFC, 0x7FF8, 0xFFF0, 0x3FC0, 0x3F80, 0x1E00};
    const int odd = j & 1;
#pragma unroll
    for (int ntl = 0; ntl < 2; ++ntl) {
        const int nt = 2 * h + ntl;
        const int row_e = 4 * nt + 2 * io;
        const uint32_t me = RM[4 * nt + 2 * io];
        const uint32_t mo = RM[4 * nt + 2 * io + 1];
        const uint32_t be  = (me >> (2 * j)) & 1u;
        const uint32_t bo0 = (mo >> (2 * j)) & 1u;
        const uint32_t bo1 = (mo >> (2 * j + 1)) & 1u;
#pragma unroll
        for (int rr = 0; rr < 4; ++rr) {
            int o = wid * 16 + q * 4 + rr;
            float up = acc[0][ntl][rr] + bias0[rr];
            float lf = acc[1][ntl][rr] + bias1[rr];
            float rt = acc[2][ntl][rr] + bias2[rr];
            up = be  ? up : 0.f;
            lf = bo0 ? lf : 0.f;
            rt = bo1 ? rt : 0.f;
            float up_o = __shfl_xor(up, 1);
            float lf_o = __shfl_xor(lf, 1);
            float rt_o = __shfl_xor(rt, 1);
            f32x4 sv;
            sv[0] = odd ? lf_o : up;
            sv[1] = odd ? rt_o : 0.f;
            sv[2] = odd ? lf   : up_o;
            sv[3] = odd ? rt   : 0.f;
            float* p = out + (((size_t)b * 64 + o) * 256 + (row_e + odd) * 16 + 4 * (j >> 1));
            __builtin_nontemporal_store(sv, (f32x4*)p);
        }
    }
}

extern "C" void kernel_launch(void* const* d_in, const int* in_sizes, int n_in,
                              void* d_out, int out_size, void* d_ws, size_t ws_size,
                              hipStream_t stream) {
    const float* x  = (const float*)d_in[0];
    const float* wu = (const float*)d_in[1];
    const float* bu = (const float*)d_in[2];
    const float* wl = (const float*)d_in[3];
    const float* bl = (const float*)d_in[4];
    const float* wr = (const float*)d_in[5];
    const float* br = (const float*)d_in[6];
    float* out   = (float*)d_out;
    uint16_t* pw = (uint16_t*)d_ws;          // 245,760 B of packed bf16 weights

    int B = in_sizes[0] / 16384;             // 2048
    pack_w<<<(NFRAG + 255) / 256, 256, 0, stream>>>(wu, wl, wr, pw);
    kagome_main<<<B * 2, 256, 0, stream>>>(x, pw, bu, bl, br, out);
}

// Round 9
// 56.975 us; speedup vs baseline: 1.3494x; 1.3494x over previous
//
#include <hip/hip_runtime.h>
#include <stdint.h>
#include <stddef.h>

typedef __attribute__((ext_vector_type(4))) float    f32x4;
typedef __attribute__((ext_vector_type(4))) uint32_t u32x4;
typedef __attribute__((ext_vector_type(8))) __bf16   bf16x8;

#define CGS   5200      // bytes per channel-group plane (R5 known-good)
#define NFRAG 15360     // 15 (dir,tap) * 2 kk * 4 mtile * 64 lanes

// tap (kr,kc) per f = dir*5+tap  (dir: 0=up,1=left,2=right)
__device__ __constant__ uint8_t TAPR[15] = {0,0,1,2,2, 1,2,2,2,3, 1,2,2,2,3};
__device__ __constant__ uint8_t TAPC[15] = {0,1,1,1,2, 1,0,1,2,1, 1,1,2,3,3};

// periodic-boundary copies on padded 18x18 (dst <- src), sources never destinations
__device__ __constant__ uint8_t PDR[30] = {1,1,2,3,4,4,6,7,8,10,11,12,14,14,15,16,17,17,16,15,14,14,12,10,8,6,4,4,3,2};
__device__ __constant__ uint8_t PDC[30] = {3,5,7,9,10,11,13,13,14,15,15,16,15,16,15,14,13,11,9,7,6,5,3,2,1,0,0,1,1,2};
__device__ __constant__ uint8_t PSR[30] = {13,13,14,15,16,16,6,7,8,10,11,12,2,2,3,4,5,5,4,3,2,2,12,10,8,6,16,16,15,14};
__device__ __constant__ uint8_t PSC[30] = {15,5,7,9,10,11,1,1,2,3,3,4,3,4,3,2,1,11,9,7,6,5,15,14,13,12,12,13,13,14};

__device__ __forceinline__ uint32_t pk2(float a, float b) {
    return (uint32_t)__builtin_bit_cast(uint16_t, (__bf16)a)
         | ((uint32_t)__builtin_bit_cast(uint16_t, (__bf16)b) << 16);
}

// ---------------- weight packing: A-fragment layout for mfma_f32_16x16x32_bf16 ----------------
__global__ __launch_bounds__(256) void pack_w(const float* __restrict__ wu,
                                              const float* __restrict__ wl,
                                              const float* __restrict__ wr,
                                              uint16_t* __restrict__ pw) {
    int fid = blockIdx.x * 256 + threadIdx.x;
    if (fid >= NFRAG) return;
    int lane = fid & 63;
    int mt   = (fid >> 6) & 3;
    int kk   = (fid >> 8) & 1;
    int td   = fid >> 9;                 // 0..14 = dir*5+tap
    const float* w = (td < 5) ? wu : (td < 10) ? wl : wr;
    int o  = mt * 16 + (lane & 15);
    int cb = kk * 32 + (lane >> 4) * 8;
    int kr = TAPR[td], kc = TAPC[td];
    const float* src = w + ((size_t)o * 64 + cb) * 16 + kr * 4 + kc;
    uint32_t d[4];
#pragma unroll
    for (int p = 0; p < 4; ++p)
        d[p] = pk2(src[(2 * p) * 16], src[(2 * p + 1) * 16]);
    u32x4 v = {d[0], d[1], d[2], d[3]};
    *(u32x4*)(pw + (size_t)fid * 8) = v;
}

// slot within a channel-group plane, column-parity split: 16 B per slot (8 channels, one pixel)
__device__ __forceinline__ int slotof(int r, int c) { return (c & 1) * 162 + r * 9 + (c >> 1); }

__global__ __launch_bounds__(256, 3) void kagome_main(const float* __restrict__ x,
                                                      const uint16_t* __restrict__ pw,
                                                      const float* __restrict__ bu,
                                                      const float* __restrict__ bl,
                                                      const float* __restrict__ br,
                                                      float* __restrict__ out) {
    __shared__ __align__(16) uint8_t lds[8 * CGS];
    const int tid = threadIdx.x;
    const int b   = blockIdx.x;

    // compute lane decomposition (also used for hoisted bias loads)
    const int l   = tid & 63;
    const int wid = tid >> 6;
    const int q   = l >> 4;        // k-quarter
    const int io  = (l >> 3) & 1;  // row-pair within n-tile
    const int j   = l & 7;         // conv output column

    // hoisted bias loads: one dwordx4 per direction
    const int ob = wid * 16 + q * 4;
    f32x4 bias0 = *(const f32x4*)(bu + ob);
    f32x4 bias1 = *(const f32x4*)(bl + ob);
    f32x4 bias2 = *(const f32x4*)(br + ob);

    // ---- phase 1a: stage interior (16x16) as bf16. Task = (channel-group, pixel-quad).
    {
        const float* xb = x + (size_t)b * 16384;
#pragma unroll
        for (int i = 0; i < 2; ++i) {
            const int t    = i * 256 + tid;
            const int cg   = t >> 6;        // 0..7 (uniform per wave)
            const int quad = t & 63;        // row r0 = quad>>2, cols 4*(quad&3)..+3
            const int r0   = quad >> 2;
            const int qc   = quad & 3;
            f32x4 v[8];
#pragma unroll
            for (int ch = 0; ch < 8; ++ch)
                v[ch] = *(const f32x4*)(xb + (cg * 8 + ch) * 256 + quad * 4);
            uint8_t* base = lds + cg * CGS;
#pragma unroll
            for (int e = 0; e < 4; ++e) {
                const int pc   = 4 * qc + e + 1;              // padded col
                const int slot = slotof(r0 + 1, pc);
                u32x4 w = {pk2(v[0][e], v[1][e]), pk2(v[2][e], v[3][e]),
                           pk2(v[4][e], v[5][e]), pk2(v[6][e], v[7][e])};
                *(u32x4*)(base + slot * 16) = w;
            }
        }
        // ---- phase 1b: zero all 68 border sites (disjoint from interior) ----
        u32x4 z = {0, 0, 0, 0};
        for (int idx = tid; idx < 68 * 8; idx += 256) {
            int s = idx >> 3, cg = idx & 7;
            int r, c;
            if (s < 18)      { r = 0;  c = s; }
            else if (s < 36) { r = 17; c = s - 18; }
            else             { int k2 = s - 36; r = 1 + (k2 >> 1); c = (k2 & 1) * 17; }
            *(u32x4*)(lds + cg * CGS + slotof(r, c) * 16) = z;
        }
    }
    __syncthreads();
    // ---- phase 2: periodic copies (sources are original interior values) ----
    if (tid < 240) {
        int pair = tid >> 3, cg = tid & 7;
        int sa = slotof(PSR[pair], PSC[pair]);
        int da = slotof(PDR[pair], PDC[pair]);
        u32x4 v = *(const u32x4*)(lds + cg * CGS + sa * 16);
        *(u32x4*)(lds + cg * CGS + da * 16) = v;
    }
    __syncthreads();

    // ---- compute ----
    f32x4 acc[3][4];
#pragma unroll
    for (int d2 = 0; d2 < 3; ++d2)
#pragma unroll
        for (int n2 = 0; n2 < 4; ++n2) acc[d2][n2] = (f32x4){0.f, 0.f, 0.f, 0.f};

    const int bbase = q * CGS + io * 288 + j * 16;
    const uint16_t* pwl = pw + (size_t)l * 8;

    constexpr uint32_t RM[16] = {0x0008, 0x003C, 0x00FC, 0x01FE, 0x07FF, 0x0FFF, 0x0FFF, 0x1FFE,
                                 0x3FFE, 0xBFFC, 0xBFFC, 0x7FF8, 0xFFF0, 0x3FC0, 0x3F80, 0x1E00};
    const int odd = j & 1;

#define BRD(dr, dc) __builtin_bit_cast(bf16x8, *(const u32x4*)(lb + ((dc) & 1) * 2592 + (4 * nt + (dr)) * 144 + ((dc) >> 1) * 16))
#define DO_MFMAS(KK)                                                                           \
            bf16x8 b00 = BRD(0, 0);                                                            \
            acc[0][nt] = __builtin_amdgcn_mfma_f32_16x16x32_bf16(aw[0], b00, acc[0][nt], 0, 0, 0); \
            bf16x8 b01 = BRD(0, 1);                                                            \
            acc[0][nt] = __builtin_amdgcn_mfma_f32_16x16x32_bf16(aw[1], b01, acc[0][nt], 0, 0, 0); \
            bf16x8 b11 = BRD(1, 1);                                                            \
            acc[0][nt] = __builtin_amdgcn_mfma_f32_16x16x32_bf16(aw[2],  b11, acc[0][nt], 0, 0, 0); \
            acc[1][nt] = __builtin_amdgcn_mfma_f32_16x16x32_bf16(aw[5],  b11, acc[1][nt], 0, 0, 0); \
            acc[2][nt] = __builtin_amdgcn_mfma_f32_16x16x32_bf16(aw[10], b11, acc[2][nt], 0, 0, 0); \
            bf16x8 b20 = BRD(2, 0);                                                            \
            acc[1][nt] = __builtin_amdgcn_mfma_f32_16x16x32_bf16(aw[6],  b20, acc[1][nt], 0, 0, 0); \
            bf16x8 b21 = BRD(2, 1);                                                            \
            acc[0][nt] = __builtin_amdgcn_mfma_f32_16x16x32_bf16(aw[3],  b21, acc[0][nt], 0, 0, 0); \
            acc[1][nt] = __builtin_amdgcn_mfma_f32_16x16x32_bf16(aw[7],  b21, acc[1][nt], 0, 0, 0); \
            acc[2][nt] = __builtin_amdgcn_mfma_f32_16x16x32_bf16(aw[11], b21, acc[2][nt], 0, 0, 0); \
            bf16x8 b22 = BRD(2, 2);                                                            \
            acc[0][nt] = __builtin_amdgcn_mfma_f32_16x16x32_bf16(aw[4],  b22, acc[0][nt], 0, 0, 0); \
            acc[1][nt] = __builtin_amdgcn_mfma_f32_16x16x32_bf16(aw[8],  b22, acc[1][nt], 0, 0, 0); \
            acc[2][nt] = __builtin_amdgcn_mfma_f32_16x16x32_bf16(aw[12], b22, acc[2][nt], 0, 0, 0); \
            bf16x8 b23 = BRD(2, 3);                                                            \
            acc[2][nt] = __builtin_amdgcn_mfma_f32_16x16x32_bf16(aw[13], b23, acc[2][nt], 0, 0, 0); \
            bf16x8 b31 = BRD(3, 1);                                                            \
            acc[1][nt] = __builtin_amdgcn_mfma_f32_16x16x32_bf16(aw[9],  b31, acc[1][nt], 0, 0, 0); \
            bf16x8 b33 = BRD(3, 3);                                                            \
            acc[2][nt] = __builtin_amdgcn_mfma_f32_16x16x32_bf16(aw[14], b33, acc[2][nt], 0, 0, 0);

    // kk = 0: pure MFMA
    {
        bf16x8 aw[15];
#pragma unroll
        for (int f2 = 0; f2 < 15; ++f2) {
            u32x4 t = *(const u32x4*)(pwl + (size_t)((f2 * 2 + 0) * 4 + wid) * 512);
            aw[f2] = __builtin_bit_cast(bf16x8, t);
        }
        const uint8_t* lb = lds + bbase;
#pragma unroll
        for (int nt = 0; nt < 4; ++nt) {
            DO_MFMAS(0)
        }
    }
    // kk = 1: per-nt MFMA + fused epilogue store (spreads VMEM stores across compute)
    {
        bf16x8 aw[15];
#pragma unroll
        for (int f2 = 0; f2 < 15; ++f2) {
            u32x4 t = *(const u32x4*)(pwl + (size_t)((f2 * 2 + 1) * 4 + wid) * 512);
            aw[f2] = __builtin_bit_cast(bf16x8, t);
        }
        const uint8_t* lb = lds + 4 * CGS + bbase;
#pragma unroll
        for (int nt = 0; nt < 4; ++nt) {
            DO_MFMAS(1)
            // ---- epilogue for this nt ----
            const int row_e = 4 * nt + 2 * io;
            const uint32_t me = io ? RM[4 * nt + 2] : RM[4 * nt + 0];
            const uint32_t mo = io ? RM[4 * nt + 3] : RM[4 * nt + 1];
            const uint32_t be  = (me >> (2 * j)) & 1u;
            const uint32_t bo0 = (mo >> (2 * j)) & 1u;
            const uint32_t bo1 = (mo >> (2 * j + 1)) & 1u;
#pragma unroll
            for (int r = 0; r < 4; ++r) {
                int o = ob + r;
                float up = acc[0][nt][r] + bias0[r];
                float lf = acc[1][nt][r] + bias1[r];
                float rt = acc[2][nt][r] + bias2[r];
                up = be  ? up : 0.f;
                lf = bo0 ? lf : 0.f;
                rt = bo1 ? rt : 0.f;
                float up_o = __shfl_xor(up, 1);
                float lf_o = __shfl_xor(lf, 1);
                float rt_o = __shfl_xor(rt, 1);
                f32x4 v;
                v[0] = odd ? lf_o : up;
                v[1] = odd ? rt_o : 0.f;
                v[2] = odd ? lf   : up_o;
                v[3] = odd ? rt   : 0.f;
                float* p = out + (((size_t)b * 64 + o) * 256 + (row_e + odd) * 16 + 4 * (j >> 1));
                __builtin_nontemporal_store(v, (f32x4*)p);
            }
        }
    }
#undef DO_MFMAS
#undef BRD
}

extern "C" void kernel_launch(void* const* d_in, const int* in_sizes, int n_in,
                              void* d_out, int out_size, void* d_ws, size_t ws_size,
                              hipStream_t stream) {
    const float* x  = (const float*)d_in[0];
    const float* wu = (const float*)d_in[1];
    const float* bu = (const float*)d_in[2];
    const float* wl = (const float*)d_in[3];
    const float* bl = (const float*)d_in[4];
    const float* wr = (const float*)d_in[5];
    const float* br = (const float*)d_in[6];
    float* out   = (float*)d_out;
    uint16_t* pw = (uint16_t*)d_ws;          // 245,760 B of packed bf16 weights

    int B = in_sizes[0] / 16384;             // 2048
    pack_w<<<(NFRAG + 255) / 256, 256, 0, stream>>>(wu, wl, wr, pw);
    kagome_main<<<B, 256, 0, stream>>>(x, pw, bu, bl, br, out);
}